// Round 16
// baseline (32.861 us; speedup 1.0000x reference)
//
#include <hip/hip_runtime.h>

#define OUTN 400
#define THRESH 0.7f
#define BB 32
#define HH 512
#define WW 512
#define CC 3
#define BIGI 0x7FFFFFFF

#define PXPB      (OUTN * OUTN)         // 160000 px per batch
#define TPB       320                   // resize threads per block (5 waves)
#define PXB       (TPB * 2)             // 640 px per block -> 250 blocks/batch exact
#define BLKS_PB   (PXPB / PXB)          // 250
#define NXCD      8
#define RGRID     (BB * BLKS_PB)        // 8000 resize blocks, divisible by 8

typedef float vfloat4 __attribute__((ext_vector_type(4)));

// ---------------------------------------------------------------------------
// One block per batch: border pre-check, then (only if inconclusive) a full
// in-block scan. Writes FINAL bounds directly.
// ---------------------------------------------------------------------------
__global__ void __launch_bounds__(256) bounds_final_kernel(
        const float* __restrict__ tensor,
        int4* __restrict__ finals) {
    const int b = blockIdx.x;
    const int t = threadIdx.x;
    const float* tb = tensor + (size_t)b * (HH * WW);

    bool r0any = false, r1any = false, c0any = false, c1any = false;

    if (t < 128) {
        vfloat4 v = ((const vfloat4*)tb)[t];
        r0any = (v.x > THRESH) | (v.y > THRESH) | (v.z > THRESH) | (v.w > THRESH);
    } else {
        vfloat4 v = ((const vfloat4*)(tb + (size_t)(HH - 1) * WW))[t - 128];
        r1any = (v.x > THRESH) | (v.y > THRESH) | (v.z > THRESH) | (v.w > THRESH);
    }
    {
        float a0 = tb[(size_t)t * WW];
        float a1 = tb[(size_t)(t + 256) * WW];
        c0any = (a0 > THRESH) | (a1 > THRESH);
        float b0 = tb[(size_t)t * WW + (WW - 1)];
        float b1 = tb[(size_t)(t + 256) * WW + (WW - 1)];
        c1any = (b0 > THRESH) | (b1 > THRESH);
    }

    __shared__ int s[4];
    if (t == 0) { s[0] = 0; s[1] = 0; s[2] = 0; s[3] = 0; }
    __syncthreads();
    bool a0 = __any(r0any), a1 = __any(r1any), a2 = __any(c0any), a3 = __any(c1any);
    if ((t & 63) == 0) {
        if (a0) atomicOr(&s[0], 1);
        if (a1) atomicOr(&s[1], 1);
        if (a2) atomicOr(&s[2], 1);
        if (a3) atomicOr(&s[3], 1);
    }
    __syncthreads();

    if (s[0] && s[1] && s[2] && s[3]) {
        if (t == 0) {
            int4 f; f.x = 0; f.y = HH - 1; f.z = 0; f.w = WW - 1;
            finals[b] = f;
        }
        return;
    }

    // ---- fallback: full scan of this batch within the block (rare path) ----
    int minR = BIGI, maxR = -1, minC = BIGI, maxC = -1;
    const vfloat4* base = (const vfloat4*)tb;
    for (int p = t; p < (HH * WW) / 4; p += 256) {
        vfloat4 v = __builtin_nontemporal_load(base + p);
        int row  = p >> 7;                // 128 float4 per row
        int col0 = (p & 127) * 4;
        int mask = (v.x > THRESH ? 1 : 0) | (v.y > THRESH ? 2 : 0)
                 | (v.z > THRESH ? 4 : 0) | (v.w > THRESH ? 8 : 0);
        if (mask) {
            minR = min(minR, row);
            maxR = max(maxR, row);
            minC = min(minC, col0 + __builtin_ctz(mask));
            maxC = max(maxC, col0 + (31 - __builtin_clz(mask)));
        }
    }

    #pragma unroll
    for (int off = 32; off > 0; off >>= 1) {
        minR = min(minR, __shfl_down(minR, off));
        maxR = max(maxR, __shfl_down(maxR, off));
        minC = min(minC, __shfl_down(minC, off));
        maxC = max(maxC, __shfl_down(maxC, off));
    }

    __shared__ int r[4];
    if (t == 0) { r[0] = BIGI; r[1] = -1; r[2] = BIGI; r[3] = -1; }
    __syncthreads();
    if ((t & 63) == 0) {
        atomicMin(&r[0], minR); atomicMax(&r[1], maxR);
        atomicMin(&r[2], minC); atomicMax(&r[3], maxC);
    }
    __syncthreads();
    if (t == 0) {
        int4 f;
        if (r[1] >= 0) { f.x = r[0]; f.y = r[1]; } else { f.x = 0; f.y = HH - 1; }
        if (r[3] >= 0) { f.z = r[2]; f.w = r[3]; } else { f.z = 0; f.w = WW - 1; }
        finals[b] = f;   // all-false axis => [0, n-1] (argmax semantics)
    }
}

__device__ inline void ld3(const float* __restrict__ p, float* d) {
    d[0] = p[0]; d[1] = p[1]; d[2] = p[2];
}

// Wave-chunked 2 px/thread: thread t handles px {waveBase + lane} and
// {waveBase + 64 + lane} — per-INSTRUCTION lanes stay 64 consecutive px
// (~15.3 B/lane gather stride, round 15's proven TA pattern) while each
// thread now has 8 gathers in flight (2 independent px).
__global__ void __launch_bounds__(TPB) resize_kernel(
        const float* __restrict__ img,
        const int4* __restrict__ finals,
        float* __restrict__ out) {
    // bijective XCD swizzle (RGRID = 8000 divisible by 8)
    const int logical = (blockIdx.x % NXCD) * (RGRID / NXCD) + blockIdx.x / NXCD;

    const int t    = threadIdx.x;
    const int lane = t & 63;
    const int wave = t >> 6;                               // 0..4
    const int b    = logical / BLKS_PB;                    // block-uniform
    const int wbase = (logical % BLKS_PB) * PXB + wave * 128;  // wave's 128 px

    const int4 f = finals[b];                              // scalar load
    const int minR = f.x, maxR = f.y, minC = f.z, maxC = f.w;

    const float sizeR  = (float)(maxR - minR);
    const float hiClpR = fmaxf(sizeR - 1.0f, 0.0f);
    const int   imaxR  = max(maxR - minR - 1, 0);
    const float sizeC  = (float)(maxC - minC);
    const float hiClpC = fmaxf(sizeC - 1.0f, 0.0f);
    const int   jmaxC  = max(maxC - minC - 1, 0);

    const float* __restrict__ ib = img + (size_t)b * (HH * WW * CC);  // SGPR base

    int   rem_[2];
    int   ro0_[2], ro1_[2], c0_[2], c1_[2];
    float wr_[2], wc_[2];

    #pragma unroll
    for (int c = 0; c < 2; ++c) {
        const int rem  = wbase + c * 64 + lane;
        rem_[c] = rem;
        const int ocol = rem % OUTN;
        const int orow = rem / OUTN;

        float srcR = ((float)orow + 0.5f) * sizeR * (1.0f / OUTN) - 0.5f;
        srcR = fminf(fmaxf(srcR, 0.0f), hiClpR);
        int   i0 = (int)floorf(srcR);
        int   i1 = min(i0 + 1, imaxR);
        wr_[c] = srcR - (float)i0;
        ro0_[c] = (minR + i0) * (WW * CC);
        ro1_[c] = (minR + i1) * (WW * CC);

        float srcC = ((float)ocol + 0.5f) * sizeC * (1.0f / OUTN) - 0.5f;
        srcC = fminf(fmaxf(srcC, 0.0f), hiClpC);
        int   j0 = (int)floorf(srcC);
        int   j1 = min(j0 + 1, jmaxC);
        wc_[c] = srcC - (float)j0;
        c0_[c] = (minC + j0) * CC;
        c1_[c] = (minC + j1) * CC;
    }

    // load phase: 8 independent dwordx3 gathers (2 px x 4 texels), all issued
    float a00[2][3], a01[2][3], a10[2][3], a11[2][3];
    #pragma unroll
    for (int c = 0; c < 2; ++c) {
        ld3(ib + ro0_[c] + c0_[c], a00[c]);
        ld3(ib + ro0_[c] + c1_[c], a01[c]);
        ld3(ib + ro1_[c] + c0_[c], a10[c]);
        ld3(ib + ro1_[c] + c1_[c], a11[c]);
    }

    // blend + store (12 B contiguous per lane per chunk)
    #pragma unroll
    for (int c = 0; c < 2; ++c) {
        float wc = wc_[c], wr = wr_[c];
        float omc = 1.0f - wc, omr = 1.0f - wr;
        float res[3];
        #pragma unroll
        for (int ch = 0; ch < CC; ++ch) {
            float top = a00[c][ch] * omc + a01[c][ch] * wc;
            float bot = a10[c][ch] * omc + a11[c][ch] * wc;
            res[ch] = top * omr + bot * wr;
        }
        float* o = out + ((size_t)b * PXPB + (size_t)rem_[c]) * CC;
        __builtin_nontemporal_store(res[0], o + 0);
        __builtin_nontemporal_store(res[1], o + 1);
        __builtin_nontemporal_store(res[2], o + 2);
    }
}

extern "C" void kernel_launch(void* const* d_in, const int* in_sizes, int n_in,
                              void* d_out, int out_size, void* d_ws, size_t ws_size,
                              hipStream_t stream) {
    const float* image  = (const float*)d_in[0];
    const float* tensor = (const float*)d_in[1];
    float* out    = (float*)d_out;
    int4*  finals = (int4*)d_ws;    // 32 * 16 B

    hipLaunchKernelGGL(bounds_final_kernel, dim3(BB), dim3(256), 0, stream,
                       tensor, finals);

    hipLaunchKernelGGL(resize_kernel, dim3(RGRID), dim3(TPB), 0, stream,
                       image, finals, out);
}